// Round 1
// baseline (334.721 us; speedup 1.0000x reference)
//
#include <hip/hip_runtime.h>
#include <math.h>

#define NB 16
#define CIN 64
#define HH 112
#define WW 112
#define HW 12544
#define INIT_C 64
#define NEW_C 64
#define NE 4
#define SE_HIDN 32
#define OUTC 128
#define EPSV 1e-5f
#define TP 128
#define NT (HW / TP) /* 98 */

// ---------------- kernel 1: pooled mean of x, zero sum1 ----------------
__global__ __launch_bounds__(256) void k_pool(const float* __restrict__ x,
                                              float* __restrict__ pooled,
                                              float* __restrict__ sum1) {
    int bc = blockIdx.x;  // 0..NB*CIN-1
    const float4* p4 = (const float4*)(x + (size_t)bc * HW);
    float s = 0.f;
    for (int g = threadIdx.x; g < HW / 4; g += 256) {
        float4 v = p4[g];
        s += v.x + v.y + v.z + v.w;
    }
    for (int off = 32; off > 0; off >>= 1) s += __shfl_down(s, off, 64);
    __shared__ float ls[4];
    if ((threadIdx.x & 63) == 0) ls[threadIdx.x >> 6] = s;
    __syncthreads();
    if (threadIdx.x == 0) {
        pooled[bc] = (ls[0] + ls[1] + ls[2] + ls[3]) * (1.f / (float)HW);
        sum1[bc] = 0.f;
    }
}

// ---------------- kernel 2: dynamic 1x1 conv + BN1 + ReLU -> out[ch 0..63], sum1 ----------------
__global__ __launch_bounds__(256) void k_conv1(
    const float* __restrict__ x, const float* __restrict__ pooled,
    const float* __restrict__ rw1, const float* __restrict__ rb1,
    const float* __restrict__ w1, const float* __restrict__ bn1_g,
    const float* __restrict__ bn1_b, const float* __restrict__ bn1_m,
    const float* __restrict__ bn1_v, float* __restrict__ out,
    float* __restrict__ sum1) {
    __shared__ alignas(16) float sA[CIN * INIT_C];  // [i][o], BN scale folded
    __shared__ alignas(16) float sX[CIN * TP];      // [i][p]
    __shared__ float sShift[INIT_C];
    __shared__ float r1s[NE];
    int b = blockIdx.x / NT;
    int tile = blockIdx.x % NT;
    int p0 = tile * TP;
    int t = threadIdx.x;

    if (t < NE) {
        float acc = rb1[t];
        const float* pb = pooled + b * CIN;
        const float* rw = rw1 + t * CIN;
        for (int i = 0; i < CIN; i++) acc = fmaf(pb[i], rw[i], acc);
        r1s[t] = 1.f / (1.f + expf(-acc));
    }
    if (t >= 64 && t < 128) {
        int o = t - 64;
        float sc = bn1_g[o] * rsqrtf(bn1_v[o] + EPSV);
        sShift[o] = bn1_b[o] - bn1_m[o] * sc;
    }
    __syncthreads();  // r1s ready

    // build per-sample mixed kernel (transposed [i][o]), BN scale folded
    for (int idx = t; idx < CIN * INIT_C; idx += 256) {
        int o = idx & 63, i = idx >> 6;
        float acc = 0.f;
#pragma unroll
        for (int e = 0; e < NE; e++)
            acc = fmaf(r1s[e], w1[(e * INIT_C + o) * CIN + i], acc);
        float sc = bn1_g[o] * rsqrtf(bn1_v[o] + EPSV);
        sA[i * INIT_C + o] = acc * sc;
    }
    // stage x tile [64 ch][128 px]
    {
        const float* gx = x + (size_t)b * CIN * HW + p0;
        for (int g = t; g < CIN * TP / 4; g += 256) {
            int i = g >> 5, c4 = g & 31;
            ((float4*)sX)[g] = *(const float4*)(gx + (size_t)i * HW + (c4 << 2));
        }
    }
    __syncthreads();

    int pg = t & 31;  // pixel group of 4
    int og = t >> 5;  // channel group of 8
    float acc[8][4];
#pragma unroll
    for (int u = 0; u < 8; u++)
#pragma unroll
        for (int v = 0; v < 4; v++) acc[u][v] = 0.f;

    const float4* sX4 = (const float4*)sX;
    const float4* sA4 = (const float4*)sA;
#pragma unroll 4
    for (int i = 0; i < CIN; i++) {
        float4 xv = sX4[i * (TP / 4) + pg];
        float4 a0 = sA4[i * (INIT_C / 4) + og * 2];
        float4 a1 = sA4[i * (INIT_C / 4) + og * 2 + 1];
        float av[8] = {a0.x, a0.y, a0.z, a0.w, a1.x, a1.y, a1.z, a1.w};
#pragma unroll
        for (int u = 0; u < 8; u++) {
            acc[u][0] = fmaf(av[u], xv.x, acc[u][0]);
            acc[u][1] = fmaf(av[u], xv.y, acc[u][1]);
            acc[u][2] = fmaf(av[u], xv.z, acc[u][2]);
            acc[u][3] = fmaf(av[u], xv.w, acc[u][3]);
        }
    }

    float csum[8];
#pragma unroll
    for (int u = 0; u < 8; u++) {
        int o = og * 8 + u;
        float sh = sShift[o];
        alignas(16) float r[4];
#pragma unroll
        for (int v = 0; v < 4; v++) r[v] = fmaxf(acc[u][v] + sh, 0.f);
        *(float4*)(out + ((size_t)(b * OUTC + o)) * HW + p0 + pg * 4) =
            *(float4*)r;
        csum[u] = r[0] + r[1] + r[2] + r[3];
    }
    // reduce each channel partial over the 32 pixel-group lanes (half-wave)
#pragma unroll
    for (int u = 0; u < 8; u++) {
        float v = csum[u];
        v += __shfl_xor(v, 16, 64);
        v += __shfl_xor(v, 8, 64);
        v += __shfl_xor(v, 4, 64);
        v += __shfl_xor(v, 2, 64);
        v += __shfl_xor(v, 1, 64);
        if (pg == 0) atomicAdd(&sum1[b * INIT_C + og * 8 + u], v);
    }
}

// ---------------- kernel 3: depthwise 3x3 + BN2 + ReLU, reduce to sum2 (x2 NOT stored) ----------------
__global__ __launch_bounds__(256) void k_dwsum(
    const float* __restrict__ xin,  // = d_out, x1 in channels 0..63
    const float* __restrict__ sum1, const float* __restrict__ rw2,
    const float* __restrict__ rb2, const float* __restrict__ w2,
    const float* __restrict__ bn2_g, const float* __restrict__ bn2_b,
    const float* __restrict__ bn2_m, const float* __restrict__ bn2_v,
    float* __restrict__ sum2) {
    __shared__ alignas(16) float sIn[HW];  // full 112x112 plane, 49KB
    __shared__ float r2s[NE];
    __shared__ float kk[9];
    int c = blockIdx.x & 63;
    int b = blockIdx.x >> 6;
    int t = threadIdx.x;

    if (t < NE) {
        float acc = rb2[t];
        const float* s1 = sum1 + b * INIT_C;
        const float* rw = rw2 + t * INIT_C;
        for (int i = 0; i < INIT_C; i++)
            acc = fmaf(s1[i] * (1.f / (float)HW), rw[i], acc);
        r2s[t] = 1.f / (1.f + expf(-acc));
    }
    __syncthreads();
    if (t < 9) {
        float acc = 0.f;
#pragma unroll
        for (int e = 0; e < NE; e++)
            acc = fmaf(r2s[e], w2[(e * NEW_C + c) * 9 + t], acc);
        kk[t] = acc * (bn2_g[c] * rsqrtf(bn2_v[c] + EPSV));
    }
    // stage full plane
    const float4* src4 = (const float4*)(xin + ((size_t)(b * OUTC + c)) * HW);
    for (int g = t; g < HW / 4; g += 256) ((float4*)sIn)[g] = src4[g];
    __syncthreads();

    float sc2 = bn2_g[c] * rsqrtf(bn2_v[c] + EPSV);
    float shift = bn2_b[c] - bn2_m[c] * sc2;
    float myk[9];
#pragma unroll
    for (int j = 0; j < 9; j++) myk[j] = kk[j];

    float csum = 0.f;
    for (int g = t; g < HW / 4; g += 256) {
        int rr = g / (WW / 4);
        int c4 = (g % (WW / 4)) << 2;
#pragma unroll
        for (int v = 0; v < 4; v++) {
            int col = c4 + v;
            float acc = 0.f;
#pragma unroll
            for (int dy = 0; dy < 3; dy++) {
                int ir = rr + dy - 1;
                bool rok = (ir >= 0) && (ir < HH);
#pragma unroll
                for (int dx = 0; dx < 3; dx++) {
                    int cc = col + dx - 1;
                    float xv = (rok && cc >= 0 && cc < WW) ? sIn[ir * WW + cc] : 0.f;
                    acc = fmaf(xv, myk[dy * 3 + dx], acc);
                }
            }
            csum += fmaxf(acc + shift, 0.f);
        }
    }
    for (int off = 32; off > 0; off >>= 1) csum += __shfl_down(csum, off, 64);
    __shared__ float ls[4];
    if ((t & 63) == 0) ls[t >> 6] = csum;
    __syncthreads();
    if (t == 0) sum2[b * NEW_C + c] = ls[0] + ls[1] + ls[2] + ls[3];
}

// ---------------- kernel 4: SE gate (inline) + dw recompute + gated writes ----------------
__global__ __launch_bounds__(256) void k_final(
    const float* __restrict__ xin, const float* __restrict__ sum1,
    const float* __restrict__ sum2, const float* __restrict__ rw2,
    const float* __restrict__ rb2, const float* __restrict__ w2,
    const float* __restrict__ bn2_g, const float* __restrict__ bn2_b,
    const float* __restrict__ bn2_m, const float* __restrict__ bn2_v,
    const float* __restrict__ se_w1, const float* __restrict__ se_b1,
    const float* __restrict__ se_w2, const float* __restrict__ se_b2,
    float* __restrict__ out) {
    __shared__ alignas(16) float sIn[HW];  // full plane of x1
    __shared__ float sin_[OUTC];
    __shared__ float hvec[SE_HIDN];
    __shared__ float r2s[NE];
    __shared__ float kk[9];
    int c = blockIdx.x & 63;
    int b = blockIdx.x >> 6;
    int t = threadIdx.x;

    // phase A: SE input vector + r2
    if (t < 64) sin_[t] = sum1[b * 64 + t] * (1.f / (float)HW);
    else if (t < 128) sin_[t] = sum2[b * 64 + (t - 64)] * (1.f / (float)HW);
    if (t >= 128 && t < 128 + NE) {
        int e = t - 128;
        float acc = rb2[e];
        const float* s1 = sum1 + b * INIT_C;
        const float* rw = rw2 + e * INIT_C;
        for (int i = 0; i < INIT_C; i++)
            acc = fmaf(s1[i] * (1.f / (float)HW), rw[i], acc);
        r2s[e] = 1.f / (1.f + expf(-acc));
    }
    __syncthreads();
    // phase B: hidden layer, dw coeffs, plane staging
    if (t < SE_HIDN) {
        float acc = se_b1[t];
        const float* wrow = se_w1 + t * OUTC;
#pragma unroll 4
        for (int i = 0; i < OUTC; i++) acc = fmaf(sin_[i], wrow[i], acc);
        hvec[t] = fmaxf(acc, 0.f);
    }
    if (t >= 64 && t < 73) {
        int j = t - 64;
        float acc = 0.f;
#pragma unroll
        for (int e = 0; e < NE; e++)
            acc = fmaf(r2s[e], w2[(e * NEW_C + c) * 9 + j], acc);
        kk[j] = acc * (bn2_g[c] * rsqrtf(bn2_v[c] + EPSV));
    }
    const float4* src4 = (const float4*)(xin + ((size_t)(b * OUTC + c)) * HW);
    for (int g = t; g < HW / 4; g += 256) ((float4*)sIn)[g] = src4[g];
    __syncthreads();
    // phase C: every thread computes its two gate values redundantly (64 FMA)
    float a1 = se_b2[c], a2 = se_b2[64 + c];
    {
        const float* w2a = se_w2 + c * SE_HIDN;
        const float* w2b = se_w2 + (64 + c) * SE_HIDN;
#pragma unroll 8
        for (int j = 0; j < SE_HIDN; j++) {
            float hj = hvec[j];
            a1 = fmaf(hj, w2a[j], a1);
            a2 = fmaf(hj, w2b[j], a2);
        }
    }
    float s1v = 1.f / (1.f + expf(-a1));
    float s2v = 1.f / (1.f + expf(-a2));
    float sc2 = bn2_g[c] * rsqrtf(bn2_v[c] + EPSV);
    float shift = bn2_b[c] - bn2_m[c] * sc2;
    float myk[9];
#pragma unroll
    for (int j = 0; j < 9; j++) myk[j] = kk[j];

    float* d1 = out + ((size_t)(b * OUTC + c)) * HW;
    float* d2 = out + ((size_t)(b * OUTC + 64 + c)) * HW;
    for (int g = t; g < HW / 4; g += 256) {
        int rr = g / (WW / 4);
        int c4 = (g % (WW / 4)) << 2;
        alignas(16) float o1[4], o2[4];
#pragma unroll
        for (int v = 0; v < 4; v++) {
            int col = c4 + v;
            float acc = 0.f;
#pragma unroll
            for (int dy = 0; dy < 3; dy++) {
                int ir = rr + dy - 1;
                bool rok = (ir >= 0) && (ir < HH);
#pragma unroll
                for (int dx = 0; dx < 3; dx++) {
                    int cc = col + dx - 1;
                    float xv = (rok && cc >= 0 && cc < WW) ? sIn[ir * WW + cc] : 0.f;
                    acc = fmaf(xv, myk[dy * 3 + dx], acc);
                }
            }
            float x2v = fmaxf(acc + shift, 0.f);
            o1[v] = sIn[rr * WW + col] * s1v;
            o2[v] = x2v * s2v;
        }
        *(float4*)(d1 + (size_t)rr * WW + c4) = *(float4*)o1;
        *(float4*)(d2 + (size_t)rr * WW + c4) = *(float4*)o2;
    }
}

extern "C" void kernel_launch(void* const* d_in, const int* in_sizes, int n_in,
                              void* d_out, int out_size, void* d_ws,
                              size_t ws_size, hipStream_t stream) {
    (void)in_sizes; (void)n_in; (void)out_size; (void)ws_size;
    const float* x = (const float*)d_in[0];
    const float* rw1 = (const float*)d_in[1];
    const float* rb1 = (const float*)d_in[2];
    const float* w1 = (const float*)d_in[3];
    const float* bn1_g = (const float*)d_in[4];
    const float* bn1_b = (const float*)d_in[5];
    const float* bn1_m = (const float*)d_in[6];
    const float* bn1_v = (const float*)d_in[7];
    const float* rw2 = (const float*)d_in[8];
    const float* rb2 = (const float*)d_in[9];
    const float* w2 = (const float*)d_in[10];
    const float* bn2_g = (const float*)d_in[11];
    const float* bn2_b = (const float*)d_in[12];
    const float* bn2_m = (const float*)d_in[13];
    const float* bn2_v = (const float*)d_in[14];
    const float* se_w1 = (const float*)d_in[15];
    const float* se_b1 = (const float*)d_in[16];
    const float* se_w2 = (const float*)d_in[17];
    const float* se_b2 = (const float*)d_in[18];
    float* out = (float*)d_out;
    float* ws = (float*)d_ws;
    float* pooled = ws;             // NB*CIN = 1024
    float* sum1 = ws + 1024;        // NB*INIT_C = 1024
    float* sum2 = ws + 2048;        // NB*NEW_C = 1024

    k_pool<<<NB * CIN, 256, 0, stream>>>(x, pooled, sum1);
    k_conv1<<<NB * NT, 256, 0, stream>>>(x, pooled, rw1, rb1, w1, bn1_g, bn1_b,
                                         bn1_m, bn1_v, out, sum1);
    k_dwsum<<<NB * NEW_C, 256, 0, stream>>>(out, sum1, rw2, rb2, w2, bn2_g,
                                            bn2_b, bn2_m, bn2_v, sum2);
    k_final<<<NB * NEW_C, 256, 0, stream>>>(out, sum1, sum2, rw2, rb2, w2,
                                            bn2_g, bn2_b, bn2_m, bn2_v, se_w1,
                                            se_b1, se_w2, se_b2, out);
}

// Round 2
// 307.624 us; speedup vs baseline: 1.0881x; 1.0881x over previous
//
#include <hip/hip_runtime.h>
#include <math.h>

#define NB 16
#define CIN 64
#define HH 112
#define WW 112
#define HW 12544
#define INIT_C 64
#define NEW_C 64
#define NE 4
#define SE_HIDN 32
#define OUTC 128
#define EPSV 1e-5f
#define TPX 256                 /* pixels per k_conv1 block */
#define NT (HW / TPX)           /* 49 */

// ---------------- kernel 1: pooled mean of x, zero sum1 ----------------
__global__ __launch_bounds__(256) void k_pool(const float* __restrict__ x,
                                              float* __restrict__ pooled,
                                              float* __restrict__ sum1) {
    int bc = blockIdx.x;  // 0..NB*CIN-1
    const float4* p4 = (const float4*)(x + (size_t)bc * HW);
    float s = 0.f;
    for (int g = threadIdx.x; g < HW / 4; g += 256) {
        float4 v = p4[g];
        s += v.x + v.y + v.z + v.w;
    }
    for (int off = 32; off > 0; off >>= 1) s += __shfl_down(s, off, 64);
    __shared__ float ls[4];
    if ((threadIdx.x & 63) == 0) ls[threadIdx.x >> 6] = s;
    __syncthreads();
    if (threadIdx.x == 0) {
        pooled[bc] = (ls[0] + ls[1] + ls[2] + ls[3]) * (1.f / (float)HW);
        sum1[bc] = 0.f;
    }
}

// ---------------- kernel 1b: build per-batch mixed 1x1 kernel (BN scale folded) ----------------
// k1t[b][i][o], i = input ch, o = output ch
__global__ __launch_bounds__(256) void k_prep(
    const float* __restrict__ pooled, const float* __restrict__ rw1,
    const float* __restrict__ rb1, const float* __restrict__ w1,
    const float* __restrict__ bn1_g, const float* __restrict__ bn1_v,
    float* __restrict__ k1t) {
    int b = blockIdx.x;
    int t = threadIdx.x;
    __shared__ float r1s[NE];
    if (t < NE) {
        float acc = rb1[t];
        const float* pb = pooled + b * CIN;
        const float* rw = rw1 + t * CIN;
        for (int i = 0; i < CIN; i++) acc = fmaf(pb[i], rw[i], acc);
        r1s[t] = 1.f / (1.f + expf(-acc));
    }
    __syncthreads();
    for (int idx = t; idx < CIN * INIT_C; idx += 256) {
        int o = idx & 63, i = idx >> 6;
        float acc = 0.f;
#pragma unroll
        for (int e = 0; e < NE; e++)
            acc = fmaf(r1s[e], w1[(e * INIT_C + o) * CIN + i], acc);
        float sc = bn1_g[o] * rsqrtf(bn1_v[o] + EPSV);
        k1t[b * (CIN * INIT_C) + idx] = acc * sc;
    }
}

// ---------------- kernel 2: dynamic 1x1 conv + BN1 + ReLU -> out[ch 0..63], sum1 ----------------
// block: 64 ch x 256 px, thread tile 8 ch x (4+4) px
__global__ __launch_bounds__(256, 2) void k_conv1(
    const float* __restrict__ x, const float* __restrict__ k1t,
    const float* __restrict__ bn1_g, const float* __restrict__ bn1_b,
    const float* __restrict__ bn1_m, const float* __restrict__ bn1_v,
    float* __restrict__ out, float* __restrict__ sum1) {
    __shared__ alignas(16) float sA[CIN * INIT_C];  // [i][o], 16 KB
    __shared__ alignas(16) float sX[CIN * TPX];     // [i][p], 64 KB
    __shared__ float sShift[INIT_C];
    int b = blockIdx.x / NT;
    int tile = blockIdx.x % NT;
    int p0 = tile * TPX;
    int t = threadIdx.x;

    // load prebuilt kernel (coalesced float4)
    {
        const float4* src = (const float4*)(k1t + (size_t)b * CIN * INIT_C);
        for (int g = t; g < CIN * INIT_C / 4; g += 256) ((float4*)sA)[g] = src[g];
    }
    if (t < INIT_C) {
        float sc = bn1_g[t] * rsqrtf(bn1_v[t] + EPSV);
        sShift[t] = bn1_b[t] - bn1_m[t] * sc;
    }
    // stage x tile [64 i][256 px]
    {
        const float* gx = x + (size_t)b * CIN * HW + p0;
        for (int g = t; g < CIN * TPX / 4; g += 256) {
            int i = g >> 6, c4 = g & 63;
            ((float4*)sX)[g] = *(const float4*)(gx + (size_t)i * HW + (c4 << 2));
        }
    }
    __syncthreads();

    int og = t >> 5;  // 8 channel groups of 8
    int pg = t & 31;  // 32 pixel groups; bands at pg*4 and 128+pg*4
    float acc[8][8];
#pragma unroll
    for (int u = 0; u < 8; u++)
#pragma unroll
        for (int v = 0; v < 8; v++) acc[u][v] = 0.f;

    const float4* sA4 = (const float4*)sA;
    const float4* sX4 = (const float4*)sX;
#pragma unroll 2
    for (int i = 0; i < CIN; i++) {
        float4 a0 = sA4[i * (INIT_C / 4) + og * 2];
        float4 a1 = sA4[i * (INIT_C / 4) + og * 2 + 1];
        float4 x0 = sX4[i * (TPX / 4) + pg];
        float4 x1 = sX4[i * (TPX / 4) + 32 + pg];
        float av[8] = {a0.x, a0.y, a0.z, a0.w, a1.x, a1.y, a1.z, a1.w};
        float xv[8] = {x0.x, x0.y, x0.z, x0.w, x1.x, x1.y, x1.z, x1.w};
#pragma unroll
        for (int u = 0; u < 8; u++)
#pragma unroll
            for (int v = 0; v < 8; v++)
                acc[u][v] = fmaf(av[u], xv[v], acc[u][v]);
    }

    float csum[8];
#pragma unroll
    for (int u = 0; u < 8; u++) {
        int o = og * 8 + u;
        float sh = sShift[o];
        alignas(16) float r0[4], r1[4];
#pragma unroll
        for (int v = 0; v < 4; v++) {
            r0[v] = fmaxf(acc[u][v] + sh, 0.f);
            r1[v] = fmaxf(acc[u][4 + v] + sh, 0.f);
        }
        float* dst = out + ((size_t)(b * OUTC + o)) * HW + p0;
        *(float4*)(dst + pg * 4) = *(float4*)r0;
        *(float4*)(dst + 128 + pg * 4) = *(float4*)r1;
        csum[u] = r0[0] + r0[1] + r0[2] + r0[3] + r1[0] + r1[1] + r1[2] + r1[3];
    }
#pragma unroll
    for (int u = 0; u < 8; u++) {
        float v = csum[u];
        v += __shfl_xor(v, 16, 64);
        v += __shfl_xor(v, 8, 64);
        v += __shfl_xor(v, 4, 64);
        v += __shfl_xor(v, 2, 64);
        v += __shfl_xor(v, 1, 64);
        if (pg == 0) atomicAdd(&sum1[b * INIT_C + og * 8 + u], v);
    }
}

// ---------------- depthwise 3x3 helpers: sliding 3-row window, float4 math ----------------
__device__ __forceinline__ void ldrow(const float* __restrict__ sP, int pr,
                                      int cg, float4& C, float& L, float& R) {
    const float* row = sP + pr * WW;
    C = *(const float4*)(row + cg * 4);
    int lc = cg * 4 - 1;
    lc = lc < 0 ? 0 : lc;
    float lv = row[lc];
    L = (cg == 0) ? 0.f : lv;
    int rc = cg * 4 + 4;
    rc = rc > (WW - 1) ? (WW - 1) : rc;
    float rv = row[rc];
    R = (cg == 27) ? 0.f : rv;
}

__device__ __forceinline__ float4 dw9(const float4 c0, float l0, float r0,
                                      const float4 c1, float l1, float r1,
                                      const float4 c2, float l2, float r2,
                                      const float* __restrict__ K) {
    float4 o;
    o.x = fmaf(K[0], l0, fmaf(K[1], c0.x, fmaf(K[2], c0.y,
          fmaf(K[3], l1, fmaf(K[4], c1.x, fmaf(K[5], c1.y,
          fmaf(K[6], l2, fmaf(K[7], c2.x, K[8] * c2.y))))))));
    o.y = fmaf(K[0], c0.x, fmaf(K[1], c0.y, fmaf(K[2], c0.z,
          fmaf(K[3], c1.x, fmaf(K[4], c1.y, fmaf(K[5], c1.z,
          fmaf(K[6], c2.x, fmaf(K[7], c2.y, K[8] * c2.z))))))));
    o.z = fmaf(K[0], c0.y, fmaf(K[1], c0.z, fmaf(K[2], c0.w,
          fmaf(K[3], c1.y, fmaf(K[4], c1.z, fmaf(K[5], c1.w,
          fmaf(K[6], c2.y, fmaf(K[7], c2.z, K[8] * c2.w))))))));
    o.w = fmaf(K[0], c0.z, fmaf(K[1], c0.w, fmaf(K[2], r0,
          fmaf(K[3], c1.z, fmaf(K[4], c1.w, fmaf(K[5], r1,
          fmaf(K[6], c2.z, fmaf(K[7], c2.w, K[8] * r2))))))));
    return o;
}

#define PROWS (HH + 2) /* 114 */

// ---------------- kernel 3: depthwise 3x3 + BN2 + ReLU -> sum2 only ----------------
__global__ __launch_bounds__(256) void k_dwsum(
    const float* __restrict__ xin, const float* __restrict__ sum1,
    const float* __restrict__ rw2, const float* __restrict__ rb2,
    const float* __restrict__ w2, const float* __restrict__ bn2_g,
    const float* __restrict__ bn2_b, const float* __restrict__ bn2_m,
    const float* __restrict__ bn2_v, float* __restrict__ sum2) {
    __shared__ alignas(16) float sP[PROWS * WW];  // padded plane, ~51 KB
    __shared__ float r2s[NE];
    __shared__ float kks[9];
    int c = blockIdx.x & 63;
    int b = blockIdx.x >> 6;
    int t = threadIdx.x;

    if (t < NE) {
        float acc = rb2[t];
        const float* s1 = sum1 + b * INIT_C;
        const float* rw = rw2 + t * INIT_C;
        for (int i = 0; i < INIT_C; i++)
            acc = fmaf(s1[i] * (1.f / (float)HW), rw[i], acc);
        r2s[t] = 1.f / (1.f + expf(-acc));
    }
    // halo rows zero
    if (t < WW / 4) {
        float4 z = {0.f, 0.f, 0.f, 0.f};
        ((float4*)sP)[t] = z;
        ((float4*)(sP + (PROWS - 1) * WW))[t] = z;
    }
    __syncthreads();
    if (t < 9) {
        float acc = 0.f;
#pragma unroll
        for (int e = 0; e < NE; e++)
            acc = fmaf(r2s[e], w2[(e * NEW_C + c) * 9 + t], acc);
        kks[t] = acc * (bn2_g[c] * rsqrtf(bn2_v[c] + EPSV));
    }
    const float4* src4 = (const float4*)(xin + ((size_t)(b * OUTC + c)) * HW);
    float4* dst4 = (float4*)(sP + WW);
    for (int g = t; g < HW / 4; g += 256) dst4[g] = src4[g];
    __syncthreads();

    float sc2 = bn2_g[c] * rsqrtf(bn2_v[c] + EPSV);
    float shift = bn2_b[c] - bn2_m[c] * sc2;
    float myk[9];
#pragma unroll
    for (int j = 0; j < 9; j++) myk[j] = kks[j];

    int cg = t & 31;    // 28 active column groups
    int band = t >> 5;  // 8 bands x 14 rows
    float csum = 0.f;
    if (cg < 28) {
        int pr0 = band * 14;
        float4 C[3];
        float L[3], R[3];
        ldrow(sP, pr0, cg, C[0], L[0], R[0]);
        ldrow(sP, pr0 + 1, cg, C[1], L[1], R[1]);
#pragma unroll
        for (int k = 0; k < 14; k++) {
            int s0 = k % 3, s1 = (k + 1) % 3, s2 = (k + 2) % 3;
            ldrow(sP, pr0 + k + 2, cg, C[s2], L[s2], R[s2]);
            float4 o = dw9(C[s0], L[s0], R[s0], C[s1], L[s1], R[s1],
                           C[s2], L[s2], R[s2], myk);
            csum += fmaxf(o.x + shift, 0.f) + fmaxf(o.y + shift, 0.f) +
                    fmaxf(o.z + shift, 0.f) + fmaxf(o.w + shift, 0.f);
        }
    }
    for (int off = 32; off > 0; off >>= 1) csum += __shfl_down(csum, off, 64);
    __shared__ float ls[4];
    if ((t & 63) == 0) ls[t >> 6] = csum;
    __syncthreads();
    if (t == 0) sum2[b * NEW_C + c] = ls[0] + ls[1] + ls[2] + ls[3];
}

// ---------------- kernel 4: SE gate + dw recompute + gated writes ----------------
__global__ __launch_bounds__(256) void k_final(
    const float* __restrict__ xin, const float* __restrict__ sum1,
    const float* __restrict__ sum2, const float* __restrict__ rw2,
    const float* __restrict__ rb2, const float* __restrict__ w2,
    const float* __restrict__ bn2_g, const float* __restrict__ bn2_b,
    const float* __restrict__ bn2_m, const float* __restrict__ bn2_v,
    const float* __restrict__ se_w1, const float* __restrict__ se_b1,
    const float* __restrict__ se_w2, const float* __restrict__ se_b2,
    float* __restrict__ out) {
    __shared__ alignas(16) float sP[PROWS * WW];
    __shared__ float sin_[OUTC];
    __shared__ float hvec[SE_HIDN];
    __shared__ float r2s[NE];
    __shared__ float kks[9];
    int c = blockIdx.x & 63;
    int b = blockIdx.x >> 6;
    int t = threadIdx.x;

    // phase A: SE input vector + r2
    if (t < 64) sin_[t] = sum1[b * 64 + t] * (1.f / (float)HW);
    else if (t < 128) sin_[t] = sum2[b * 64 + (t - 64)] * (1.f / (float)HW);
    if (t >= 128 && t < 128 + NE) {
        int e = t - 128;
        float acc = rb2[e];
        const float* s1 = sum1 + b * INIT_C;
        const float* rw = rw2 + e * INIT_C;
        for (int i = 0; i < INIT_C; i++)
            acc = fmaf(s1[i] * (1.f / (float)HW), rw[i], acc);
        r2s[e] = 1.f / (1.f + expf(-acc));
    }
    if (t >= 160 && t < 160 + WW / 4) {
        float4 z = {0.f, 0.f, 0.f, 0.f};
        ((float4*)sP)[t - 160] = z;
        ((float4*)(sP + (PROWS - 1) * WW))[t - 160] = z;
    }
    __syncthreads();
    // phase B: hidden layer, dw coeffs, plane staging
    if (t < SE_HIDN) {
        float acc = se_b1[t];
        const float* wrow = se_w1 + t * OUTC;
#pragma unroll 4
        for (int i = 0; i < OUTC; i++) acc = fmaf(sin_[i], wrow[i], acc);
        hvec[t] = fmaxf(acc, 0.f);
    }
    if (t >= 64 && t < 73) {
        int j = t - 64;
        float acc = 0.f;
#pragma unroll
        for (int e = 0; e < NE; e++)
            acc = fmaf(r2s[e], w2[(e * NEW_C + c) * 9 + j], acc);
        kks[j] = acc * (bn2_g[c] * rsqrtf(bn2_v[c] + EPSV));
    }
    const float4* src4 = (const float4*)(xin + ((size_t)(b * OUTC + c)) * HW);
    float4* pdst4 = (float4*)(sP + WW);
    for (int g = t; g < HW / 4; g += 256) pdst4[g] = src4[g];
    __syncthreads();
    // phase C: redundant per-thread gate computation (64 FMA)
    float a1 = se_b2[c], a2 = se_b2[64 + c];
    {
        const float* w2a = se_w2 + c * SE_HIDN;
        const float* w2b = se_w2 + (64 + c) * SE_HIDN;
#pragma unroll 8
        for (int j = 0; j < SE_HIDN; j++) {
            float hj = hvec[j];
            a1 = fmaf(hj, w2a[j], a1);
            a2 = fmaf(hj, w2b[j], a2);
        }
    }
    float s1v = 1.f / (1.f + expf(-a1));
    float s2v = 1.f / (1.f + expf(-a2));
    float sc2 = bn2_g[c] * rsqrtf(bn2_v[c] + EPSV);
    float shift = bn2_b[c] - bn2_m[c] * sc2;
    float myk[9];
#pragma unroll
    for (int j = 0; j < 9; j++) myk[j] = kks[j];

    int cg = t & 31;
    int band = t >> 5;
    if (cg < 28) {
        float* d1 = out + ((size_t)(b * OUTC + c)) * HW;
        float* d2 = out + ((size_t)(b * OUTC + 64 + c)) * HW;
        int pr0 = band * 14;
        float4 C[3];
        float L[3], R[3];
        ldrow(sP, pr0, cg, C[0], L[0], R[0]);
        ldrow(sP, pr0 + 1, cg, C[1], L[1], R[1]);
#pragma unroll
        for (int k = 0; k < 14; k++) {
            int s0 = k % 3, s1 = (k + 1) % 3, s2 = (k + 2) % 3;
            ldrow(sP, pr0 + k + 2, cg, C[s2], L[s2], R[s2]);
            float4 o = dw9(C[s0], L[s0], R[s0], C[s1], L[s1], R[s1],
                           C[s2], L[s2], R[s2], myk);
            float4 x1v = C[s1];  // mid row center = x1
            float4 o1, o2;
            o1.x = x1v.x * s1v; o1.y = x1v.y * s1v;
            o1.z = x1v.z * s1v; o1.w = x1v.w * s1v;
            o2.x = fmaxf(o.x + shift, 0.f) * s2v;
            o2.y = fmaxf(o.y + shift, 0.f) * s2v;
            o2.z = fmaxf(o.z + shift, 0.f) * s2v;
            o2.w = fmaxf(o.w + shift, 0.f) * s2v;
            int row = band * 14 + k;
            *(float4*)(d1 + (size_t)row * WW + cg * 4) = o1;
            *(float4*)(d2 + (size_t)row * WW + cg * 4) = o2;
        }
    }
}

extern "C" void kernel_launch(void* const* d_in, const int* in_sizes, int n_in,
                              void* d_out, int out_size, void* d_ws,
                              size_t ws_size, hipStream_t stream) {
    (void)in_sizes; (void)n_in; (void)out_size; (void)ws_size;
    const float* x = (const float*)d_in[0];
    const float* rw1 = (const float*)d_in[1];
    const float* rb1 = (const float*)d_in[2];
    const float* w1 = (const float*)d_in[3];
    const float* bn1_g = (const float*)d_in[4];
    const float* bn1_b = (const float*)d_in[5];
    const float* bn1_m = (const float*)d_in[6];
    const float* bn1_v = (const float*)d_in[7];
    const float* rw2 = (const float*)d_in[8];
    const float* rb2 = (const float*)d_in[9];
    const float* w2 = (const float*)d_in[10];
    const float* bn2_g = (const float*)d_in[11];
    const float* bn2_b = (const float*)d_in[12];
    const float* bn2_m = (const float*)d_in[13];
    const float* bn2_v = (const float*)d_in[14];
    const float* se_w1 = (const float*)d_in[15];
    const float* se_b1 = (const float*)d_in[16];
    const float* se_w2 = (const float*)d_in[17];
    const float* se_b2 = (const float*)d_in[18];
    float* out = (float*)d_out;
    float* ws = (float*)d_ws;
    float* pooled = ws;        // 1024
    float* sum1 = ws + 1024;   // 1024
    float* sum2 = ws + 2048;   // 1024
    float* k1t = ws + 3072;    // 16*4096 = 65536

    k_pool<<<NB * CIN, 256, 0, stream>>>(x, pooled, sum1);
    k_prep<<<NB, 256, 0, stream>>>(pooled, rw1, rb1, w1, bn1_g, bn1_v, k1t);
    k_conv1<<<NB * NT, 256, 0, stream>>>(x, k1t, bn1_g, bn1_b, bn1_m, bn1_v,
                                         out, sum1);
    k_dwsum<<<NB * NEW_C, 256, 0, stream>>>(out, sum1, rw2, rb2, w2, bn2_g,
                                            bn2_b, bn2_m, bn2_v, sum2);
    k_final<<<NB * NEW_C, 256, 0, stream>>>(out, sum1, sum2, rw2, rb2, w2,
                                            bn2_g, bn2_b, bn2_m, bn2_v, se_w1,
                                            se_b1, se_w2, se_b2, out);
}

// Round 3
// 285.343 us; speedup vs baseline: 1.1730x; 1.0781x over previous
//
#include <hip/hip_runtime.h>
#include <math.h>

#define NB 16
#define CIN 64
#define HH 112
#define WW 112
#define HW 12544
#define INIT_C 64
#define NEW_C 64
#define NE 4
#define SE_HIDN 32
#define OUTC 128
#define EPSV 1e-5f
#define TPX 256                 /* pixels per k_conv1 block */
#define NT (HW / TPX)           /* 49 */

// ---------------- kernel 1: pooled mean of x, zero sum1 ----------------
__global__ __launch_bounds__(256) void k_pool(const float* __restrict__ x,
                                              float* __restrict__ pooled,
                                              float* __restrict__ sum1) {
    int bc = blockIdx.x;  // 0..NB*CIN-1
    const float4* p4 = (const float4*)(x + (size_t)bc * HW);
    float s = 0.f;
    for (int g = threadIdx.x; g < HW / 4; g += 256) {
        float4 v = p4[g];
        s += v.x + v.y + v.z + v.w;
    }
    for (int off = 32; off > 0; off >>= 1) s += __shfl_down(s, off, 64);
    __shared__ float ls[4];
    if ((threadIdx.x & 63) == 0) ls[threadIdx.x >> 6] = s;
    __syncthreads();
    if (threadIdx.x == 0) {
        pooled[bc] = (ls[0] + ls[1] + ls[2] + ls[3]) * (1.f / (float)HW);
        sum1[bc] = 0.f;
    }
}

// ---------------- kernel 1b: per-batch mixed 1x1 kernel, BN folded ----------------
// writes k1t[b][i][o] (o minor, for wave-uniform s_load in k_conv1) + shift1[64]
__global__ __launch_bounds__(256) void k_prep(
    const float* __restrict__ pooled, const float* __restrict__ rw1,
    const float* __restrict__ rb1, const float* __restrict__ w1,
    const float* __restrict__ bn1_g, const float* __restrict__ bn1_b,
    const float* __restrict__ bn1_m, const float* __restrict__ bn1_v,
    float* __restrict__ k1t, float* __restrict__ shift1) {
    int b = blockIdx.x;
    int t = threadIdx.x;
    __shared__ float r1s[NE];
    __shared__ float sT[64][65];  // [o][i], padded
    if (t < NE) {
        float acc = rb1[t];
        const float* pb = pooled + b * CIN;
        const float* rw = rw1 + t * CIN;
        for (int i = 0; i < CIN; i++) acc = fmaf(pb[i], rw[i], acc);
        r1s[t] = 1.f / (1.f + expf(-acc));
    }
    if (t >= 64 && t < 128) {
        int o = t - 64;
        float sc = bn1_g[o] * rsqrtf(bn1_v[o] + EPSV);
        shift1[o] = bn1_b[o] - bn1_m[o] * sc;  // all blocks write same values
    }
    __syncthreads();
    // phase 1: coalesced w1 reads (lanes over i), compute into sT[o][i]
    for (int idx = t; idx < CIN * INIT_C; idx += 256) {
        int o = idx >> 6, i = idx & 63;
        float acc = 0.f;
#pragma unroll
        for (int e = 0; e < NE; e++)
            acc = fmaf(r1s[e], w1[(e * INIT_C + o) * CIN + i], acc);
        float sc = bn1_g[o] * rsqrtf(bn1_v[o] + EPSV);
        sT[o][i] = acc * sc;
    }
    __syncthreads();
    // phase 2: coalesced k1t writes (lanes over o), layout [i][o]
    for (int idx = t; idx < CIN * INIT_C; idx += 256) {
        int i = idx >> 6, o = idx & 63;
        k1t[(b << 12) + idx] = sT[o][i];
    }
}

// ---------------- kernel 2: dynamic 1x1 conv, LDS-free streaming ----------------
// 4 waves share a 256-px span; wave w -> o in [16w,16w+16); A via wave-uniform s_load
__global__ __launch_bounds__(256, 4) void k_conv1(
    const float* __restrict__ x, const float* __restrict__ k1t,
    const float* __restrict__ shift1, float* __restrict__ out,
    float* __restrict__ sum1) {
    int b = blockIdx.x / NT;
    int tile = blockIdx.x - b * NT;
    int p0 = tile * TPX;
    int t = threadIdx.x;
    int lane = t & 63;
    int og16 = __builtin_amdgcn_readfirstlane(t >> 6) << 4;  // SGPR-uniform
    const float* Aw = k1t + (b << 12) + og16;   // uniform base, A[i*64+j]
    float shv[16];
#pragma unroll
    for (int j = 0; j < 16; j++) shv[j] = shift1[og16 + j];  // uniform loads

    const float* xp = x + (size_t)(b * CIN) * HW + p0 + (lane << 2);
    float4 acc[16];
#pragma unroll
    for (int j = 0; j < 16; j++) acc[j] = make_float4(0.f, 0.f, 0.f, 0.f);

#pragma unroll 2
    for (int i = 0; i < CIN; i++) {
        float4 xv = *(const float4*)(xp + (size_t)i * HW);
#pragma unroll
        for (int j = 0; j < 16; j++) {
            float a = Aw[i * 64 + j];  // wave-uniform -> s_load
            acc[j].x = fmaf(a, xv.x, acc[j].x);
            acc[j].y = fmaf(a, xv.y, acc[j].y);
            acc[j].z = fmaf(a, xv.z, acc[j].z);
            acc[j].w = fmaf(a, xv.w, acc[j].w);
        }
    }

    float* outbase = out + ((size_t)(b * OUTC + og16)) * HW + p0 + (lane << 2);
#pragma unroll
    for (int j = 0; j < 16; j++) {
        float4 r;
        r.x = fmaxf(acc[j].x + shv[j], 0.f);
        r.y = fmaxf(acc[j].y + shv[j], 0.f);
        r.z = fmaxf(acc[j].z + shv[j], 0.f);
        r.w = fmaxf(acc[j].w + shv[j], 0.f);
        *(float4*)(outbase + (size_t)j * HW) = r;
        float cs = r.x + r.y + r.z + r.w;
        cs += __shfl_xor(cs, 1, 64);
        cs += __shfl_xor(cs, 2, 64);
        cs += __shfl_xor(cs, 4, 64);
        cs += __shfl_xor(cs, 8, 64);
        cs += __shfl_xor(cs, 16, 64);
        cs += __shfl_xor(cs, 32, 64);
        if (lane == 0) atomicAdd(&sum1[b * INIT_C + og16 + j], cs);
    }
}

// ---------------- depthwise 3x3 helpers: sliding 3-row window, float4 math ----------------
__device__ __forceinline__ void ldrow(const float* __restrict__ sP, int pr,
                                      int cg, float4& C, float& L, float& R) {
    const float* row = sP + pr * WW;
    C = *(const float4*)(row + cg * 4);
    int lc = cg * 4 - 1;
    lc = lc < 0 ? 0 : lc;
    float lv = row[lc];
    L = (cg == 0) ? 0.f : lv;
    int rc = cg * 4 + 4;
    rc = rc > (WW - 1) ? (WW - 1) : rc;
    float rv = row[rc];
    R = (cg == 27) ? 0.f : rv;
}

__device__ __forceinline__ float4 dw9(const float4 c0, float l0, float r0,
                                      const float4 c1, float l1, float r1,
                                      const float4 c2, float l2, float r2,
                                      const float* __restrict__ K) {
    float4 o;
    o.x = fmaf(K[0], l0, fmaf(K[1], c0.x, fmaf(K[2], c0.y,
          fmaf(K[3], l1, fmaf(K[4], c1.x, fmaf(K[5], c1.y,
          fmaf(K[6], l2, fmaf(K[7], c2.x, K[8] * c2.y))))))));
    o.y = fmaf(K[0], c0.x, fmaf(K[1], c0.y, fmaf(K[2], c0.z,
          fmaf(K[3], c1.x, fmaf(K[4], c1.y, fmaf(K[5], c1.z,
          fmaf(K[6], c2.x, fmaf(K[7], c2.y, K[8] * c2.z))))))));
    o.z = fmaf(K[0], c0.y, fmaf(K[1], c0.z, fmaf(K[2], c0.w,
          fmaf(K[3], c1.y, fmaf(K[4], c1.z, fmaf(K[5], c1.w,
          fmaf(K[6], c2.y, fmaf(K[7], c2.z, K[8] * c2.w))))))));
    o.w = fmaf(K[0], c0.z, fmaf(K[1], c0.w, fmaf(K[2], r0,
          fmaf(K[3], c1.z, fmaf(K[4], c1.w, fmaf(K[5], r1,
          fmaf(K[6], c2.z, fmaf(K[7], c2.w, K[8] * r2))))))));
    return o;
}

#define PROWS (HH + 2) /* 114 */

// ---------------- kernel 3: depthwise 3x3 + BN2 + ReLU -> sum2 only ----------------
__global__ __launch_bounds__(256) void k_dwsum(
    const float* __restrict__ xin, const float* __restrict__ sum1,
    const float* __restrict__ rw2, const float* __restrict__ rb2,
    const float* __restrict__ w2, const float* __restrict__ bn2_g,
    const float* __restrict__ bn2_b, const float* __restrict__ bn2_m,
    const float* __restrict__ bn2_v, float* __restrict__ sum2) {
    __shared__ alignas(16) float sP[PROWS * WW];  // padded plane, ~51 KB
    __shared__ float r2s[NE];
    __shared__ float kks[9];
    int c = blockIdx.x & 63;
    int b = blockIdx.x >> 6;
    int t = threadIdx.x;

    if (t < NE) {
        float acc = rb2[t];
        const float* s1 = sum1 + b * INIT_C;
        const float* rw = rw2 + t * INIT_C;
        for (int i = 0; i < INIT_C; i++)
            acc = fmaf(s1[i] * (1.f / (float)HW), rw[i], acc);
        r2s[t] = 1.f / (1.f + expf(-acc));
    }
    // halo rows zero
    if (t < WW / 4) {
        float4 z = {0.f, 0.f, 0.f, 0.f};
        ((float4*)sP)[t] = z;
        ((float4*)(sP + (PROWS - 1) * WW))[t] = z;
    }
    __syncthreads();
    if (t < 9) {
        float acc = 0.f;
#pragma unroll
        for (int e = 0; e < NE; e++)
            acc = fmaf(r2s[e], w2[(e * NEW_C + c) * 9 + t], acc);
        kks[t] = acc * (bn2_g[c] * rsqrtf(bn2_v[c] + EPSV));
    }
    const float4* src4 = (const float4*)(xin + ((size_t)(b * OUTC + c)) * HW);
    float4* dst4 = (float4*)(sP + WW);
    for (int g = t; g < HW / 4; g += 256) dst4[g] = src4[g];
    __syncthreads();

    float sc2 = bn2_g[c] * rsqrtf(bn2_v[c] + EPSV);
    float shift = bn2_b[c] - bn2_m[c] * sc2;
    float myk[9];
#pragma unroll
    for (int j = 0; j < 9; j++) myk[j] = kks[j];

    int cg = t & 31;    // 28 active column groups
    int band = t >> 5;  // 8 bands x 14 rows
    float csum = 0.f;
    if (cg < 28) {
        int pr0 = band * 14;
        float4 C[3];
        float L[3], R[3];
        ldrow(sP, pr0, cg, C[0], L[0], R[0]);
        ldrow(sP, pr0 + 1, cg, C[1], L[1], R[1]);
#pragma unroll
        for (int k = 0; k < 14; k++) {
            int s0 = k % 3, s1 = (k + 1) % 3, s2 = (k + 2) % 3;
            ldrow(sP, pr0 + k + 2, cg, C[s2], L[s2], R[s2]);
            float4 o = dw9(C[s0], L[s0], R[s0], C[s1], L[s1], R[s1],
                           C[s2], L[s2], R[s2], myk);
            csum += fmaxf(o.x + shift, 0.f) + fmaxf(o.y + shift, 0.f) +
                    fmaxf(o.z + shift, 0.f) + fmaxf(o.w + shift, 0.f);
        }
    }
    for (int off = 32; off > 0; off >>= 1) csum += __shfl_down(csum, off, 64);
    __shared__ float ls[4];
    if ((t & 63) == 0) ls[t >> 6] = csum;
    __syncthreads();
    if (t == 0) sum2[b * NEW_C + c] = ls[0] + ls[1] + ls[2] + ls[3];
}

// ---------------- kernel 4: SE gate + dw recompute + gated writes ----------------
__global__ __launch_bounds__(256) void k_final(
    const float* __restrict__ xin, const float* __restrict__ sum1,
    const float* __restrict__ sum2, const float* __restrict__ rw2,
    const float* __restrict__ rb2, const float* __restrict__ w2,
    const float* __restrict__ bn2_g, const float* __restrict__ bn2_b,
    const float* __restrict__ bn2_m, const float* __restrict__ bn2_v,
    const float* __restrict__ se_w1, const float* __restrict__ se_b1,
    const float* __restrict__ se_w2, const float* __restrict__ se_b2,
    float* __restrict__ out) {
    __shared__ alignas(16) float sP[PROWS * WW];
    __shared__ float sin_[OUTC];
    __shared__ float hvec[SE_HIDN];
    __shared__ float r2s[NE];
    __shared__ float kks[9];
    int c = blockIdx.x & 63;
    int b = blockIdx.x >> 6;
    int t = threadIdx.x;

    // phase A: SE input vector + r2
    if (t < 64) sin_[t] = sum1[b * 64 + t] * (1.f / (float)HW);
    else if (t < 128) sin_[t] = sum2[b * 64 + (t - 64)] * (1.f / (float)HW);
    if (t >= 128 && t < 128 + NE) {
        int e = t - 128;
        float acc = rb2[e];
        const float* s1 = sum1 + b * INIT_C;
        const float* rw = rw2 + e * INIT_C;
        for (int i = 0; i < INIT_C; i++)
            acc = fmaf(s1[i] * (1.f / (float)HW), rw[i], acc);
        r2s[e] = 1.f / (1.f + expf(-acc));
    }
    if (t >= 160 && t < 160 + WW / 4) {
        float4 z = {0.f, 0.f, 0.f, 0.f};
        ((float4*)sP)[t - 160] = z;
        ((float4*)(sP + (PROWS - 1) * WW))[t - 160] = z;
    }
    __syncthreads();
    // phase B: hidden layer, dw coeffs, plane staging
    if (t < SE_HIDN) {
        float acc = se_b1[t];
        const float* wrow = se_w1 + t * OUTC;
#pragma unroll 4
        for (int i = 0; i < OUTC; i++) acc = fmaf(sin_[i], wrow[i], acc);
        hvec[t] = fmaxf(acc, 0.f);
    }
    if (t >= 64 && t < 73) {
        int j = t - 64;
        float acc = 0.f;
#pragma unroll
        for (int e = 0; e < NE; e++)
            acc = fmaf(r2s[e], w2[(e * NEW_C + c) * 9 + j], acc);
        kks[j] = acc * (bn2_g[c] * rsqrtf(bn2_v[c] + EPSV));
    }
    const float4* src4 = (const float4*)(xin + ((size_t)(b * OUTC + c)) * HW);
    float4* pdst4 = (float4*)(sP + WW);
    for (int g = t; g < HW / 4; g += 256) pdst4[g] = src4[g];
    __syncthreads();
    // phase C: redundant per-thread gate computation (64 FMA)
    float a1 = se_b2[c], a2 = se_b2[64 + c];
    {
        const float* w2a = se_w2 + c * SE_HIDN;
        const float* w2b = se_w2 + (64 + c) * SE_HIDN;
#pragma unroll 8
        for (int j = 0; j < SE_HIDN; j++) {
            float hj = hvec[j];
            a1 = fmaf(hj, w2a[j], a1);
            a2 = fmaf(hj, w2b[j], a2);
        }
    }
    float s1v = 1.f / (1.f + expf(-a1));
    float s2v = 1.f / (1.f + expf(-a2));
    float sc2 = bn2_g[c] * rsqrtf(bn2_v[c] + EPSV);
    float shift = bn2_b[c] - bn2_m[c] * sc2;
    float myk[9];
#pragma unroll
    for (int j = 0; j < 9; j++) myk[j] = kks[j];

    int cg = t & 31;
    int band = t >> 5;
    if (cg < 28) {
        float* d1 = out + ((size_t)(b * OUTC + c)) * HW;
        float* d2 = out + ((size_t)(b * OUTC + 64 + c)) * HW;
        int pr0 = band * 14;
        float4 C[3];
        float L[3], R[3];
        ldrow(sP, pr0, cg, C[0], L[0], R[0]);
        ldrow(sP, pr0 + 1, cg, C[1], L[1], R[1]);
#pragma unroll
        for (int k = 0; k < 14; k++) {
            int s0 = k % 3, s1 = (k + 1) % 3, s2 = (k + 2) % 3;
            ldrow(sP, pr0 + k + 2, cg, C[s2], L[s2], R[s2]);
            float4 o = dw9(C[s0], L[s0], R[s0], C[s1], L[s1], R[s1],
                           C[s2], L[s2], R[s2], myk);
            float4 x1v = C[s1];  // mid row center = x1
            float4 o1, o2;
            o1.x = x1v.x * s1v; o1.y = x1v.y * s1v;
            o1.z = x1v.z * s1v; o1.w = x1v.w * s1v;
            o2.x = fmaxf(o.x + shift, 0.f) * s2v;
            o2.y = fmaxf(o.y + shift, 0.f) * s2v;
            o2.z = fmaxf(o.z + shift, 0.f) * s2v;
            o2.w = fmaxf(o.w + shift, 0.f) * s2v;
            int row = band * 14 + k;
            *(float4*)(d1 + (size_t)row * WW + cg * 4) = o1;
            *(float4*)(d2 + (size_t)row * WW + cg * 4) = o2;
        }
    }
}

extern "C" void kernel_launch(void* const* d_in, const int* in_sizes, int n_in,
                              void* d_out, int out_size, void* d_ws,
                              size_t ws_size, hipStream_t stream) {
    (void)in_sizes; (void)n_in; (void)out_size; (void)ws_size;
    const float* x = (const float*)d_in[0];
    const float* rw1 = (const float*)d_in[1];
    const float* rb1 = (const float*)d_in[2];
    const float* w1 = (const float*)d_in[3];
    const float* bn1_g = (const float*)d_in[4];
    const float* bn1_b = (const float*)d_in[5];
    const float* bn1_m = (const float*)d_in[6];
    const float* bn1_v = (const float*)d_in[7];
    const float* rw2 = (const float*)d_in[8];
    const float* rb2 = (const float*)d_in[9];
    const float* w2 = (const float*)d_in[10];
    const float* bn2_g = (const float*)d_in[11];
    const float* bn2_b = (const float*)d_in[12];
    const float* bn2_m = (const float*)d_in[13];
    const float* bn2_v = (const float*)d_in[14];
    const float* se_w1 = (const float*)d_in[15];
    const float* se_b1 = (const float*)d_in[16];
    const float* se_w2 = (const float*)d_in[17];
    const float* se_b2 = (const float*)d_in[18];
    float* out = (float*)d_out;
    float* ws = (float*)d_ws;
    float* pooled = ws;        // 1024
    float* sum1 = ws + 1024;   // 1024
    float* sum2 = ws + 2048;   // 1024
    float* shift1 = ws + 3072; // 64 (padded to 1024)
    float* k1t = ws + 4096;    // 16*4096 = 65536

    k_pool<<<NB * CIN, 256, 0, stream>>>(x, pooled, sum1);
    k_prep<<<NB, 256, 0, stream>>>(pooled, rw1, rb1, w1, bn1_g, bn1_b, bn1_m,
                                   bn1_v, k1t, shift1);
    k_conv1<<<NB * NT, 256, 0, stream>>>(x, k1t, shift1, out, sum1);
    k_dwsum<<<NB * NEW_C, 256, 0, stream>>>(out, sum1, rw2, rb2, w2, bn2_g,
                                            bn2_b, bn2_m, bn2_v, sum2);
    k_final<<<NB * NEW_C, 256, 0, stream>>>(out, sum1, sum2, rw2, rb2, w2,
                                            bn2_g, bn2_b, bn2_m, bn2_v, se_w1,
                                            se_b1, se_w2, se_b2, out);
}